// Round 22
// baseline (39.473 us; speedup 1.0000x reference)
//
#include <hip/hip_runtime.h>
#include <math.h>

using short8 = __attribute__((ext_vector_type(8))) short;
using f32x4v = __attribute__((ext_vector_type(4))) float;

__device__ __forceinline__ short f2bf(float f) {  // fp32 -> bf16 RNE
  unsigned u = __builtin_bit_cast(unsigned, f);
  unsigned r = (u + 0x7fffu + ((u >> 16) & 1u)) >> 16;
  return (short)r;
}

// ---------------- fused prep: 5 roles (R20) + out[0] zeroing ---------------
__global__ __launch_bounds__(256) void prep_kernel(
    const float* __restrict__ kp1, const float* __restrict__ desc1,
    const float* __restrict__ desc2, const float* __restrict__ homo,
    const float* __restrict__ vism, float* __restrict__ okpd,
    float* __restrict__ visg, int* __restrict__ cntw, int* __restrict__ cellw,
    short* __restrict__ kpdb, short* __restrict__ d2t,
    float* __restrict__ stampg, float* __restrict__ loss_out,
    float inv31sq, float inv11sq, float inv5sq) {
  __shared__ short tile[64][33];
  __shared__ int cnt[32];
  __shared__ int cells[32][8];
  __shared__ float kx[32], ky[32];

  const int bid = blockIdx.x;
  const int t = threadIdx.x;

  if (bid < 512) {
    // ---- transpose + bf16: block = (n, 32-px strip q, 64-channel half) ----
    int n = bid & 7, idx = bid >> 3;
    int q = idx & 31, chalf = idx >> 5;
#pragma unroll
    for (int i = 0; i < 2; ++i) {
      int id2 = t + 256 * i;
      int c = (id2 >> 3);
      int px4 = (id2 & 7) * 4;
      float4 f = *(const float4*)(desc2 +
                                  ((size_t)n * 128 + chalf * 64 + c) * 1024 +
                                  q * 32 + px4);
      tile[c][px4] = f2bf(f.x);
      tile[c][px4 + 1] = f2bf(f.y);
      tile[c][px4 + 2] = f2bf(f.z);
      tile[c][px4 + 3] = f2bf(f.w);
    }
    __syncthreads();
    {
      int px = t >> 3;
      int ch = (t & 7) * 8;
      short8 o;
#pragma unroll
      for (int j = 0; j < 8; ++j) o[j] = tile[ch + j][px];
      *(short8*)(d2t + ((size_t)n * 1024 + q * 32 + px) * 128 + chalf * 64 +
                 ch) = o;
    }
  } else if (bid < 640) {
    // ---- vis: 4 lanes per cell, 2 rows each ----
    int idx = bid - 512;
    int n = idx & 7, seg = idx >> 3;
    int cell = seg * 64 + (t >> 2);
    int ph = cell >> 5, pw = cell & 31;
    const float* mrow =
        vism + ((size_t)n * 256 + ph * 8 + (t & 3) * 2) * 256 + pw * 8;
    float v = 1.f;
#pragma unroll
    for (int dy = 0; dy < 2; ++dy) {
      const float4* p = (const float4*)(mrow + dy * 256);
      float4 a = p[0], b = p[1];
      v *= a.x * a.y * a.z * a.w;
      v *= b.x * b.y * b.z * b.w;
    }
    v *= __shfl_xor(v, 1, 64);
    v *= __shfl_xor(v, 2, 64);
    if ((t & 3) == 0) visg[n * 1024 + cell] = v;
  } else if (bid < 1152) {
    // ---- kpd: bilinear, exact fp32 ----
    int k = (bid - 640) * 2 + (t >> 7);
    int c = t & 127;
    float b = kp1[k * 4 + 0];
    float y = kp1[k * 4 + 2] * 0.125f;
    float x = kp1[k * 4 + 3] * 0.125f;
    float x0 = fminf(fmaxf(floorf(x), 0.f), 31.f);
    float y0 = fminf(fmaxf(floorf(y), 0.f), 31.f);
    float x1 = fminf(x0 + 1.f, 31.f);
    float y1 = fminf(y0 + 1.f, 31.f);
    float wx = x - x0;
    float wy = y - y0;
    const float* dp = desc1 + ((size_t)(int)b * 128 + c) * 1024;
    const float* r0 = dp + (int)y0 * 32;
    const float* r1 = dp + (int)y1 * 32;
    float d00 = r0[(int)x0];
    float d01 = r0[(int)x1];
    float d10 = r1[(int)x0];
    float d11 = r1[(int)x1];
    float r = d00 * (1.f - wx) * (1.f - wy) + d01 * wx * (1.f - wy)
            + d10 * (1.f - wx) * wy + d11 * wx * wy;
    okpd[k * 128 + c] = r;
    kpdb[k * 128 + c] = f2bf(r);
  } else if (bid < 1408) {
    // ---- lists: 32 kp per block, scan all 1024 cells ----
    int idx = bid - 1152;
    int n = idx & 7;
    int kp0 = (idx >> 3) * 32;
    if (t < 32) {
      cnt[t] = 0;
      kx[t] = kp1[(kp0 + t) * 4 + 3];
      ky[t] = kp1[(kp0 + t) * 4 + 2];
    }
    __syncthreads();
    const float h00 = homo[n * 9 + 0], h01 = homo[n * 9 + 1], h02 = homo[n * 9 + 2];
    const float h10 = homo[n * 9 + 3], h11 = homo[n * 9 + 4], h12 = homo[n * 9 + 5];
    const float h20 = homo[n * 9 + 6], h21 = homo[n * 9 + 7], h22 = homo[n * 9 + 8];
#pragma unroll
    for (int i = 0; i < 4; ++i) {
      int cell = t + 256 * i;
      int ph = cell >> 5, pw = cell & 31;
      float gx = (float)(pw * 8 + 4);
      float gy = (float)(ph * 8 + 4);
      float w0 = h00 * gx + h01 * gy + h02;
      float w1 = h10 * gx + h11 * gy + h12;
      float w2 = h20 * gx + h21 * gy + h22;
      float wx_ = w0 / w2, wy_ = w1 / w2;
#pragma unroll
      for (int kt = 0; kt < 32; ++kt) {
        float dx = kx[kt] - wx_;
        float dy = ky[kt] - wy_;
        if (dx * dx + dy * dy <= 56.25f) {
          int pos = atomicAdd(&cnt[kt], 1);
          if (pos < 8) cells[kt][pos] = cell;
        }
      }
    }
    __syncthreads();
    if (t < 32) cntw[n * 1024 + kp0 + t] = min(cnt[t], 8);
    cellw[(size_t)(n * 1024 + kp0) * 8 + t] = cells[t >> 3][t & 7];
  } else {
    // ---- stamp table (once) + zero the loss accumulator for this call ----
    if (t == 0) loss_out[0] = 0.f;
    for (int i = t; i < 63 * 64; i += 256) {
      int yy = i >> 6, xx = i & 63;
      int dy = yy - 16, dx = xx - 16;
      float v = 0.f;
      if ((unsigned)dy < 31u && (unsigned)dx < 31u) {
        float ay = (float)(dy - 15), ax = (float)(dx - 15);
        float r2 = ay * ay + ax * ax;
        v = expf(r2 * (-1.f / 98.f)) * inv31sq;
        if (dy >= 10 && dy <= 20 && dx >= 10 && dx <= 20)
          v += expf(r2 * (-1.f / 32.f)) * inv11sq;
        if (dy >= 13 && dy <= 17 && dx >= 13 && dx <= 17)
          v += expf(r2 * (-1.f / 8.f)) * inv5sq;
      }
      stampg[i] = v;
    }
  }
}

// ---------------- main: R21 structure + direct atomicAdd epilogue ----------
// block = (n, kp-tile 64, px-tile 128); wave w: 16 kp x 128 px, 8 nt.
// B tile staged via async global_load_lds (linear dest + inverse-swizzled
// source, involution u^=(px&7)); af hoisted; blur reads global stamp table
// (L1-resident). Block sum goes straight to out[0] via one atomicAdd.
__global__ __launch_bounds__(256, 4) void main_kernel(
    const float* __restrict__ kp1, const float* __restrict__ homo,
    const float* __restrict__ visg, const int* __restrict__ cntw,
    const int* __restrict__ cellw, const short* __restrict__ kpdb,
    const short* __restrict__ d2t, const float* __restrict__ stampg,
    float* __restrict__ loss_out) {
  __shared__ short sB[128 * 128];   // 32 KB; slot(px,u) holds logical u^(px&7)
  __shared__ float s_wx[128], s_wy[128], s_vis[128];
  __shared__ float s_kpx[64], s_kpy[64];
  __shared__ int s_cnt[64];
  __shared__ int s_cells[512];
  __shared__ float s_red[4];

  const int t = threadIdx.x;
  const int bid = blockIdx.x;
  const int n = bid & 7;               // XCD-locality swizzle (matches prep)
  const int rem = bid >> 3;
  const int k0 = (rem & 15) * 64;
  const int p0 = (rem >> 4) * 128;
  const int ph0 = p0 >> 5;

  const int w = t >> 6, l = t & 63;
  const int lr = l & 15, lh = l >> 4;

  // ---- B staging: async global->LDS, issued FIRST (stays in VMEM queue) ---
  {
    const short* gB = d2t + ((size_t)n * 1024 + p0) * 128;  // 32 KB linear
#pragma unroll
    for (int i = 0; i < 8; ++i) {
      int idx = t + 256 * i;            // linear 16B-unit index = px*16 + u
      int px = idx >> 4, u = idx & 15;
      int srcIdx = (px << 4) | (u ^ (px & 7));   // inverse swizzle (involution)
      const short* src = gB + srcIdx * 8;
      short* dstBase = sB + (size_t)(w * 64 + 256 * i) * 8;
      __builtin_amdgcn_global_load_lds(
          (const __attribute__((address_space(1))) unsigned*)src,
          (__attribute__((address_space(3))) unsigned*)dstBase, 16, 0, 0);
    }
  }

  // ---- af loads (independent; overlap with async staging) ----
  const short* Abase = kpdb + (size_t)(k0 + (w << 4) + lr) * 128 + lh * 8;
  short8 af[4];
#pragma unroll
  for (int ks = 0; ks < 4; ++ks) af[ks] = *(const short8*)(Abase + ks * 32);

  // ---- metadata staging ----
  if (t < 128) {
    int pxg = p0 + t;
    int ph = pxg >> 5, pw = pxg & 31;
    float gx = (float)(pw * 8 + 4);
    float gy = (float)(ph * 8 + 4);
    float w0 = homo[n * 9 + 0] * gx + homo[n * 9 + 1] * gy + homo[n * 9 + 2];
    float w1 = homo[n * 9 + 3] * gx + homo[n * 9 + 4] * gy + homo[n * 9 + 5];
    float w2 = homo[n * 9 + 6] * gx + homo[n * 9 + 7] * gy + homo[n * 9 + 8];
    s_wx[t] = w0 / w2;
    s_wy[t] = w1 / w2;
    s_vis[t] = visg[n * 1024 + pxg];
  }
  if (t < 64) {
    float4 kr = ((const float4*)kp1)[k0 + t];   // one 16B load per kp row
    s_kpx[t] = kr.w;
    s_kpy[t] = kr.z;
    s_cnt[t] = cntw[n * 1024 + k0 + t];
  }
  if (t < 128)
    ((int4*)s_cells)[t] =
        ((const int4*)(cellw + (size_t)(n * 1024 + k0) * 8))[t];
  __syncthreads();

  // ---- MFMA: af resident; B fragments from swizzled LDS ----
  f32x4v acc[8];
#pragma unroll
  for (int nt = 0; nt < 8; ++nt) {
    acc[nt] = (f32x4v){0.f, 0.f, 0.f, 0.f};
    int pxl = nt * 16 + lr;
    const char* brow = (const char*)sB + pxl * 256;
    int sw = (pxl & 7);
#pragma unroll
    for (int ks = 0; ks < 4; ++ks) {
      short8 bf = *(const short8*)(brow + (((lh + 4 * ks) ^ sw) << 4));
      acc[nt] =
          __builtin_amdgcn_mfma_f32_16x16x32_bf16(af[ks], bf, acc[nt], 0, 0, 0);
    }
  }

  // ---- blur: cell-outer, unrolled px-inner, global stamp (L1-resident) ----
  float blur[8][4];
#pragma unroll
  for (int nt = 0; nt < 8; ++nt)
#pragma unroll
    for (int r = 0; r < 4; ++r) blur[nt][r] = 0.f;
#pragma unroll
  for (int r = 0; r < 4; ++r) {
    int kp = (w << 4) + (lh << 2) + r;
    int cn = s_cnt[kp];
    for (int j = 0; j < cn; ++j) {      // <=4 iters (disk covers <=4 cells)
      int cell = s_cells[kp * 8 + j];
      const float* Tp = stampg + (ph0 - (cell >> 5) + 31) * 64 +
                        (lr - (cell & 31) + 31);
#pragma unroll
      for (int nt = 0; nt < 8; ++nt)
        blur[nt][r] += Tp[(nt >> 1) * 64 + (nt & 1) * 16];
    }
  }

  // ---- hinge + block reduce + single atomic ----
  const float POSL = 112.30770111083984f;  // 374.359 * 0.3
  float lp = 0.f;
#pragma unroll
  for (int nt = 0; nt < 8; ++nt) {
    int pxl = nt * 16 + lr;
    float wx_ = s_wx[pxl], wy_ = s_wy[pxl], vv = s_vis[pxl];
#pragma unroll
    for (int r = 0; r < 4; ++r) {
      int kp = (w << 4) + (lh << 2) + r;
      float dx = s_kpx[kp] - wx_;
      float dy = s_kpy[kp] - wy_;
      float sval = (dx * dx + dy * dy <= 56.25f) ? 1.f : 0.f;
      float dot = acc[nt][r];
      float pos = fmaxf(1.f - dot, 0.f);
      float neg = fmaxf(dot - 0.2f, 0.f);
      lp = fmaf(POSL * sval * vv, pos, lp);
      lp = fmaf((blur[nt][r] - 3.f * sval) * vv, neg, lp);
    }
  }
#pragma unroll
  for (int off = 32; off > 0; off >>= 1) lp += __shfl_down(lp, off, 64);
  if ((t & 63) == 0) s_red[t >> 6] = lp;
  __syncthreads();
  if (t == 0) {
    float tot = (s_red[0] + s_red[1]) + (s_red[2] + s_red[3]);
    atomicAdd(loss_out, tot * (float)(1.0 / (1024.0 * 374.359)));
  }
}

// ---------------------------------------------------------------------------
extern "C" void kernel_launch(void* const* d_in, const int* in_sizes, int n_in,
                              void* d_out, int out_size, void* d_ws, size_t ws_size,
                              hipStream_t stream) {
  (void)in_sizes; (void)n_in; (void)out_size; (void)ws_size;
  const float* kp1   = (const float*)d_in[0];
  const float* desc1 = (const float*)d_in[1];
  const float* desc2 = (const float*)d_in[2];
  const float* homo  = (const float*)d_in[3];
  const float* vism  = (const float*)d_in[4];
  float* out = (float*)d_out;

  float* visg   = (float*)d_ws;              // 8192 f32
  int*   cntw   = (int*)(visg + 8192);       // 8192 i32
  int*   cellw  = cntw + 8192;               // 65536 i32
  short* kpdb   = (short*)(cellw + 65536);   // 131072 bf16
  short* d2t    = kpdb + 131072;             // 1048576 bf16
  float* stampg = (float*)(d2t + 1048576);   // 4032 f32

  auto ksum = [](int ks, double sigma) {
    double sum = 0.0;
    for (int i = 0; i < ks; ++i) {
      double x = i - (ks - 1) / 2.0;
      sum += exp(-(x * x) / (2.0 * sigma * sigma));
    }
    return sum;
  };
  double s31 = ksum(31, 7.0), s11 = ksum(11, 4.0), s5 = ksum(5, 2.0);
  float inv31sq = (float)(1.0 / (s31 * s31));
  float inv11sq = (float)(1.0 / (s11 * s11));
  float inv5sq  = (float)(1.0 / (s5 * s5));

  prep_kernel<<<dim3(1409), dim3(256), 0, stream>>>(
      kp1, desc1, desc2, homo, vism, out + 1, visg, cntw, cellw, kpdb, d2t,
      stampg, out, inv31sq, inv11sq, inv5sq);
  main_kernel<<<dim3(1024), dim3(256), 0, stream>>>(
      kp1, homo, visg, cntw, cellw, kpdb, d2t, stampg, out);
}

// Round 23
// 33.789 us; speedup vs baseline: 1.1682x; 1.1682x over previous
//
#include <hip/hip_runtime.h>
#include <math.h>

using short8 = __attribute__((ext_vector_type(8))) short;
using f32x4v = __attribute__((ext_vector_type(4))) float;

__device__ __forceinline__ short f2bf(float f) {  // fp32 -> bf16 RNE
  unsigned u = __builtin_bit_cast(unsigned, f);
  unsigned r = (u + 0x7fffu + ((u >> 16) & 1u)) >> 16;
  return (short)r;
}

// ---------------- fused prep: 5 roles (R20, unchanged) ---------------------
__global__ __launch_bounds__(256) void prep_kernel(
    const float* __restrict__ kp1, const float* __restrict__ desc1,
    const float* __restrict__ desc2, const float* __restrict__ homo,
    const float* __restrict__ vism, float* __restrict__ okpd,
    float* __restrict__ visg, int* __restrict__ cntw, int* __restrict__ cellw,
    short* __restrict__ kpdb, short* __restrict__ d2t,
    float* __restrict__ stampg,
    float inv31sq, float inv11sq, float inv5sq) {
  __shared__ short tile[64][33];
  __shared__ int cnt[32];
  __shared__ int cells[32][8];
  __shared__ float kx[32], ky[32];

  const int bid = blockIdx.x;
  const int t = threadIdx.x;

  if (bid < 512) {
    // ---- transpose + bf16: block = (n, 32-px strip q, 64-channel half) ----
    int n = bid & 7, idx = bid >> 3;
    int q = idx & 31, chalf = idx >> 5;
#pragma unroll
    for (int i = 0; i < 2; ++i) {
      int id2 = t + 256 * i;
      int c = (id2 >> 3);
      int px4 = (id2 & 7) * 4;
      float4 f = *(const float4*)(desc2 +
                                  ((size_t)n * 128 + chalf * 64 + c) * 1024 +
                                  q * 32 + px4);
      tile[c][px4] = f2bf(f.x);
      tile[c][px4 + 1] = f2bf(f.y);
      tile[c][px4 + 2] = f2bf(f.z);
      tile[c][px4 + 3] = f2bf(f.w);
    }
    __syncthreads();
    {
      int px = t >> 3;
      int ch = (t & 7) * 8;
      short8 o;
#pragma unroll
      for (int j = 0; j < 8; ++j) o[j] = tile[ch + j][px];
      *(short8*)(d2t + ((size_t)n * 1024 + q * 32 + px) * 128 + chalf * 64 +
                 ch) = o;
    }
  } else if (bid < 640) {
    // ---- vis: 4 lanes per cell, 2 rows each ----
    int idx = bid - 512;
    int n = idx & 7, seg = idx >> 3;
    int cell = seg * 64 + (t >> 2);
    int ph = cell >> 5, pw = cell & 31;
    const float* mrow =
        vism + ((size_t)n * 256 + ph * 8 + (t & 3) * 2) * 256 + pw * 8;
    float v = 1.f;
#pragma unroll
    for (int dy = 0; dy < 2; ++dy) {
      const float4* p = (const float4*)(mrow + dy * 256);
      float4 a = p[0], b = p[1];
      v *= a.x * a.y * a.z * a.w;
      v *= b.x * b.y * b.z * b.w;
    }
    v *= __shfl_xor(v, 1, 64);
    v *= __shfl_xor(v, 2, 64);
    if ((t & 3) == 0) visg[n * 1024 + cell] = v;
  } else if (bid < 1152) {
    // ---- kpd: bilinear, exact fp32 ----
    int k = (bid - 640) * 2 + (t >> 7);
    int c = t & 127;
    float b = kp1[k * 4 + 0];
    float y = kp1[k * 4 + 2] * 0.125f;
    float x = kp1[k * 4 + 3] * 0.125f;
    float x0 = fminf(fmaxf(floorf(x), 0.f), 31.f);
    float y0 = fminf(fmaxf(floorf(y), 0.f), 31.f);
    float x1 = fminf(x0 + 1.f, 31.f);
    float y1 = fminf(y0 + 1.f, 31.f);
    float wx = x - x0;
    float wy = y - y0;
    const float* dp = desc1 + ((size_t)(int)b * 128 + c) * 1024;
    const float* r0 = dp + (int)y0 * 32;
    const float* r1 = dp + (int)y1 * 32;
    float d00 = r0[(int)x0];
    float d01 = r0[(int)x1];
    float d10 = r1[(int)x0];
    float d11 = r1[(int)x1];
    float r = d00 * (1.f - wx) * (1.f - wy) + d01 * wx * (1.f - wy)
            + d10 * (1.f - wx) * wy + d11 * wx * wy;
    okpd[k * 128 + c] = r;
    kpdb[k * 128 + c] = f2bf(r);
  } else if (bid < 1408) {
    // ---- lists: 32 kp per block, scan all 1024 cells ----
    int idx = bid - 1152;
    int n = idx & 7;
    int kp0 = (idx >> 3) * 32;
    if (t < 32) {
      cnt[t] = 0;
      kx[t] = kp1[(kp0 + t) * 4 + 3];
      ky[t] = kp1[(kp0 + t) * 4 + 2];
    }
    __syncthreads();
    const float h00 = homo[n * 9 + 0], h01 = homo[n * 9 + 1], h02 = homo[n * 9 + 2];
    const float h10 = homo[n * 9 + 3], h11 = homo[n * 9 + 4], h12 = homo[n * 9 + 5];
    const float h20 = homo[n * 9 + 6], h21 = homo[n * 9 + 7], h22 = homo[n * 9 + 8];
#pragma unroll
    for (int i = 0; i < 4; ++i) {
      int cell = t + 256 * i;
      int ph = cell >> 5, pw = cell & 31;
      float gx = (float)(pw * 8 + 4);
      float gy = (float)(ph * 8 + 4);
      float w0 = h00 * gx + h01 * gy + h02;
      float w1 = h10 * gx + h11 * gy + h12;
      float w2 = h20 * gx + h21 * gy + h22;
      float wx_ = w0 / w2, wy_ = w1 / w2;
#pragma unroll
      for (int kt = 0; kt < 32; ++kt) {
        float dx = kx[kt] - wx_;
        float dy = ky[kt] - wy_;
        if (dx * dx + dy * dy <= 56.25f) {
          int pos = atomicAdd(&cnt[kt], 1);
          if (pos < 8) cells[kt][pos] = cell;
        }
      }
    }
    __syncthreads();
    if (t < 32) cntw[n * 1024 + kp0 + t] = min(cnt[t], 8);
    cellw[(size_t)(n * 1024 + kp0) * 8 + t] = cells[t >> 3][t & 7];
  } else {
    // ---- stamp table (once): 63x64 padded, core at [16..46]^2 ----
    for (int i = t; i < 63 * 64; i += 256) {
      int yy = i >> 6, xx = i & 63;
      int dy = yy - 16, dx = xx - 16;
      float v = 0.f;
      if ((unsigned)dy < 31u && (unsigned)dx < 31u) {
        float ay = (float)(dy - 15), ax = (float)(dx - 15);
        float r2 = ay * ay + ax * ax;
        v = expf(r2 * (-1.f / 98.f)) * inv31sq;
        if (dy >= 10 && dy <= 20 && dx >= 10 && dx <= 20)
          v += expf(r2 * (-1.f / 32.f)) * inv11sq;
        if (dy >= 13 && dy <= 17 && dx >= 13 && dx <= 17)
          v += expf(r2 * (-1.f / 8.f)) * inv5sq;
      }
      stampg[i] = v;
    }
  }
}

// ---------------- main: R19 structure + async global_load_lds staging ------
// block = (n, kp-tile 64, px-tile 128); wave w: 16 kp x 128 px, 8 nt.
// B tile staged via global_load_lds width=16: LINEAR LDS dest (wave-uniform
// base + lane*16) + INVERSE-swizzled global source (involution u^=(px&7)),
// read side unchanged (rule #21 both-sides pattern). LDS 37.1 KB, 4 blk/CU.
__global__ __launch_bounds__(256, 4) void main_kernel(
    const float* __restrict__ kp1, const float* __restrict__ homo,
    const float* __restrict__ visg, const int* __restrict__ cntw,
    const int* __restrict__ cellw, const short* __restrict__ kpdb,
    const short* __restrict__ d2t, const float* __restrict__ stampg,
    float* __restrict__ part) {
  __shared__ short sB[128 * 128];   // 32 KB; slot(px,u) holds logical u^(px&7)
  __shared__ float s_wx[128], s_wy[128], s_vis[128];
  __shared__ float s_kpx[64], s_kpy[64];
  __shared__ int s_cnt[64];
  __shared__ int s_cells[512];
  __shared__ float s_red[4];

  const int t = threadIdx.x;
  const int bid = blockIdx.x;
  const int n = bid & 7;               // XCD-locality swizzle (matches prep)
  const int rem = bid >> 3;
  const int k0 = (rem & 15) * 64;
  const int p0 = (rem >> 4) * 128;
  const int ph0 = p0 >> 5;

  const int w = t >> 6, l = t & 63;
  const int lr = l & 15, lh = l >> 4;

  // ---- B staging: async global->LDS, issued FIRST (stays in VMEM queue) ---
  {
    const short* gB = d2t + ((size_t)n * 1024 + p0) * 128;  // 32 KB linear
#pragma unroll
    for (int i = 0; i < 8; ++i) {
      int idx = t + 256 * i;            // linear 16B-unit index = px*16 + u
      int px = idx >> 4, u = idx & 15;
      int srcIdx = (px << 4) | (u ^ (px & 7));   // inverse swizzle (involution)
      const short* src = gB + srcIdx * 8;
      // wave-uniform LDS base for this iteration; HW adds lane*16
      short* dstBase = sB + (size_t)(w * 64 + 256 * i) * 8;
      __builtin_amdgcn_global_load_lds(
          (const __attribute__((address_space(1))) unsigned*)src,
          (__attribute__((address_space(3))) unsigned*)dstBase, 16, 0, 0);
    }
  }

  // ---- af loads (independent; overlap with async staging) ----
  const short* Abase = kpdb + (size_t)(k0 + (w << 4) + lr) * 128 + lh * 8;
  short8 af[4];
#pragma unroll
  for (int ks = 0; ks < 4; ++ks) af[ks] = *(const short8*)(Abase + ks * 32);

  // ---- metadata staging ----
  if (t < 128) {
    int pxg = p0 + t;
    int ph = pxg >> 5, pw = pxg & 31;
    float gx = (float)(pw * 8 + 4);
    float gy = (float)(ph * 8 + 4);
    float w0 = homo[n * 9 + 0] * gx + homo[n * 9 + 1] * gy + homo[n * 9 + 2];
    float w1 = homo[n * 9 + 3] * gx + homo[n * 9 + 4] * gy + homo[n * 9 + 5];
    float w2 = homo[n * 9 + 6] * gx + homo[n * 9 + 7] * gy + homo[n * 9 + 8];
    s_wx[t] = w0 / w2;
    s_wy[t] = w1 / w2;
    s_vis[t] = visg[n * 1024 + pxg];
  }
  if (t < 64) {
    float4 kr = ((const float4*)kp1)[k0 + t];   // one 16B load per kp row
    s_kpx[t] = kr.w;
    s_kpy[t] = kr.z;
    s_cnt[t] = cntw[n * 1024 + k0 + t];
  }
  if (t < 128)
    ((int4*)s_cells)[t] =
        ((const int4*)(cellw + (size_t)(n * 1024 + k0) * 8))[t];
  __syncthreads();

  // ---- MFMA: af resident; B fragments from swizzled LDS ----
  f32x4v acc[8];
#pragma unroll
  for (int nt = 0; nt < 8; ++nt) {
    acc[nt] = (f32x4v){0.f, 0.f, 0.f, 0.f};
    int pxl = nt * 16 + lr;
    const char* brow = (const char*)sB + pxl * 256;
    int sw = (pxl & 7);
#pragma unroll
    for (int ks = 0; ks < 4; ++ks) {
      short8 bf = *(const short8*)(brow + (((lh + 4 * ks) ^ sw) << 4));
      acc[nt] =
          __builtin_amdgcn_mfma_f32_16x16x32_bf16(af[ks], bf, acc[nt], 0, 0, 0);
    }
  }

  // ---- blur: cell-outer, unrolled px-inner, global stamp (L1-resident) ----
  float blur[8][4];
#pragma unroll
  for (int nt = 0; nt < 8; ++nt)
#pragma unroll
    for (int r = 0; r < 4; ++r) blur[nt][r] = 0.f;
#pragma unroll
  for (int r = 0; r < 4; ++r) {
    int kp = (w << 4) + (lh << 2) + r;
    int cn = s_cnt[kp];
    for (int j = 0; j < cn; ++j) {      // <=4 iters (disk covers <=4 cells)
      int cell = s_cells[kp * 8 + j];
      const float* Tp = stampg + (ph0 - (cell >> 5) + 31) * 64 +
                        (lr - (cell & 31) + 31);
#pragma unroll
      for (int nt = 0; nt < 8; ++nt)
        blur[nt][r] += Tp[(nt >> 1) * 64 + (nt & 1) * 16];
    }
  }

  // ---- hinge + block reduce ----
  const float POSL = 112.30770111083984f;  // 374.359 * 0.3
  float lp = 0.f;
#pragma unroll
  for (int nt = 0; nt < 8; ++nt) {
    int pxl = nt * 16 + lr;
    float wx_ = s_wx[pxl], wy_ = s_wy[pxl], vv = s_vis[pxl];
#pragma unroll
    for (int r = 0; r < 4; ++r) {
      int kp = (w << 4) + (lh << 2) + r;
      float dx = s_kpx[kp] - wx_;
      float dy = s_kpy[kp] - wy_;
      float sval = (dx * dx + dy * dy <= 56.25f) ? 1.f : 0.f;
      float dot = acc[nt][r];
      float pos = fmaxf(1.f - dot, 0.f);
      float neg = fmaxf(dot - 0.2f, 0.f);
      lp = fmaf(POSL * sval * vv, pos, lp);
      lp = fmaf((blur[nt][r] - 3.f * sval) * vv, neg, lp);
    }
  }
#pragma unroll
  for (int off = 32; off > 0; off >>= 1) lp += __shfl_down(lp, off, 64);
  if ((t & 63) == 0) s_red[t >> 6] = lp;
  __syncthreads();
  if (t == 0)
    part[bid] = (s_red[0] + s_red[1]) + (s_red[2] + s_red[3]);
}

// ---------------- final: sum 1024 partials -> loss -------------------------
__global__ void reduce_kernel(const float* __restrict__ part,
                              float* __restrict__ out) {
  __shared__ float s_red[4];
  int t = threadIdx.x;
  float v = part[t] + part[t + 256] + part[t + 512] + part[t + 768];
#pragma unroll
  for (int off = 32; off > 0; off >>= 1) v += __shfl_down(v, off, 64);
  if ((t & 63) == 0) s_red[t >> 6] = v;
  __syncthreads();
  if (t == 0)
    out[0] = ((s_red[0] + s_red[1]) + (s_red[2] + s_red[3])) *
             (float)(1.0 / (1024.0 * 374.359));
}

// ---------------------------------------------------------------------------
extern "C" void kernel_launch(void* const* d_in, const int* in_sizes, int n_in,
                              void* d_out, int out_size, void* d_ws, size_t ws_size,
                              hipStream_t stream) {
  (void)in_sizes; (void)n_in; (void)out_size; (void)ws_size;
  const float* kp1   = (const float*)d_in[0];
  const float* desc1 = (const float*)d_in[1];
  const float* desc2 = (const float*)d_in[2];
  const float* homo  = (const float*)d_in[3];
  const float* vism  = (const float*)d_in[4];
  float* out = (float*)d_out;

  float* visg   = (float*)d_ws;              // 8192 f32
  int*   cntw   = (int*)(visg + 8192);       // 8192 i32
  int*   cellw  = cntw + 8192;               // 65536 i32
  short* kpdb   = (short*)(cellw + 65536);   // 131072 bf16
  short* d2t    = kpdb + 131072;             // 1048576 bf16
  float* part   = (float*)(d2t + 1048576);   // 1024 f32
  float* stampg = part + 1024;               // 4032 f32

  auto ksum = [](int ks, double sigma) {
    double sum = 0.0;
    for (int i = 0; i < ks; ++i) {
      double x = i - (ks - 1) / 2.0;
      sum += exp(-(x * x) / (2.0 * sigma * sigma));
    }
    return sum;
  };
  double s31 = ksum(31, 7.0), s11 = ksum(11, 4.0), s5 = ksum(5, 2.0);
  float inv31sq = (float)(1.0 / (s31 * s31));
  float inv11sq = (float)(1.0 / (s11 * s11));
  float inv5sq  = (float)(1.0 / (s5 * s5));

  prep_kernel<<<dim3(1409), dim3(256), 0, stream>>>(
      kp1, desc1, desc2, homo, vism, out + 1, visg, cntw, cellw, kpdb, d2t,
      stampg, inv31sq, inv11sq, inv5sq);
  main_kernel<<<dim3(1024), dim3(256), 0, stream>>>(
      kp1, homo, visg, cntw, cellw, kpdb, d2t, stampg, part);
  reduce_kernel<<<dim3(1), dim3(256), 0, stream>>>(part, out);
}